// Round 1
// baseline (187.455 us; speedup 1.0000x reference)
//
#include <hip/hip_runtime.h>

#define BATCH 2
#define T_LEN 1024
#define D_IN  1024
#define D_ST  16
#define CHUNKS 8
#define CLEN  (T_LEN / CHUNKS)   // 128

__device__ __forceinline__ float softplus_f(float x) {
    // log1p(exp(x)) stable: max(x,0) + log(1+exp(-|x|)); abs err < 1e-7
    return fmaxf(x, 0.0f) + __logf(1.0f + __expf(-fabsf(x)));
}

// Kernel 1: causal depthwise conv (K=4, left-pad 3) + bias + SiLU -> xc (B,T,D)
__global__ __launch_bounds__(256) void conv_silu_k(
    const float* __restrict__ x, const float* __restrict__ cw,
    const float* __restrict__ cb, float* __restrict__ xc)
{
    int tid = blockIdx.x * 256 + threadIdx.x;   // B*(T/4)*D threads
    int d  = tid & (D_IN - 1);
    int g  = tid >> 10;                          // (b, t/4)
    int t0 = (g & (T_LEN/4 - 1)) << 2;
    int b  = g >> 8;
    float w0 = cw[d*4+0], w1 = cw[d*4+1], w2 = cw[d*4+2], w3 = cw[d*4+3];
    float bias = cb[d];
    int base = (b*T_LEN + t0)*D_IN + d;
    float xv[7];
    #pragma unroll
    for (int i = 0; i < 7; i++) {
        int t = t0 - 3 + i;
        xv[i] = (t >= 0) ? x[base + (i-3)*D_IN] : 0.0f;
    }
    #pragma unroll
    for (int r = 0; r < 4; r++) {
        float a = fmaf(xv[r], w0, fmaf(xv[r+1], w1, fmaf(xv[r+2], w2, fmaf(xv[r+3], w3, bias))));
        float sg = 1.0f / (1.0f + __expf(-a));
        xc[base + r*D_IN] = a * sg;
    }
}

// Kernel 2: proj (B,T,32) = xc @ x_proj_w^T  -> Bss,Css ; then dt = sp(sp(B@dtw^T + b))
// block = 256 threads = 8 rows x 32 p ; grid = B*T/8
__global__ __launch_bounds__(256) void proj_dt_k(
    const float* __restrict__ xc, const float* __restrict__ xpw,
    const float* __restrict__ dtw, const float* __restrict__ dtb,
    float* __restrict__ Bss, float* __restrict__ Css, float* __restrict__ dtp)
{
    __shared__ float sproj[8][32];
    int p = threadIdx.x & 31;
    int r = threadIdx.x >> 5;
    int row0 = blockIdx.x * 8;
    int row  = row0 + r;
    const float4* xr = (const float4*)(xc + (size_t)row * D_IN);
    const float4* wr = (const float4*)(xpw + (size_t)p * D_IN);
    float acc = 0.0f;
    #pragma unroll 8
    for (int k = 0; k < D_IN/4; k++) {
        float4 a = xr[k], w = wr[k];
        acc = fmaf(a.x, w.x, acc);
        acc = fmaf(a.y, w.y, acc);
        acc = fmaf(a.z, w.z, acc);
        acc = fmaf(a.w, w.w, acc);
    }
    sproj[r][p] = acc;
    if (p < D_ST) Bss[row*D_ST + p] = acc;
    else          Css[row*D_ST + (p - D_ST)] = acc;
    __syncthreads();

    #pragma unroll
    for (int j = 0; j < 4; j++) {
        int d = threadIdx.x + j*256;
        const float4* wd = (const float4*)(dtw + d*D_ST);
        float4 q0 = wd[0], q1 = wd[1], q2 = wd[2], q3 = wd[3];
        float bias = dtb[d];
        #pragma unroll
        for (int rr = 0; rr < 8; rr++) {
            const float* Bp = sproj[rr];
            float z = bias;
            z = fmaf(Bp[0],  q0.x, z); z = fmaf(Bp[1],  q0.y, z);
            z = fmaf(Bp[2],  q0.z, z); z = fmaf(Bp[3],  q0.w, z);
            z = fmaf(Bp[4],  q1.x, z); z = fmaf(Bp[5],  q1.y, z);
            z = fmaf(Bp[6],  q1.z, z); z = fmaf(Bp[7],  q1.w, z);
            z = fmaf(Bp[8],  q2.x, z); z = fmaf(Bp[9],  q2.y, z);
            z = fmaf(Bp[10], q2.z, z); z = fmaf(Bp[11], q2.w, z);
            z = fmaf(Bp[12], q3.x, z); z = fmaf(Bp[13], q3.y, z);
            z = fmaf(Bp[14], q3.z, z); z = fmaf(Bp[15], q3.w, z);
            z = softplus_f(softplus_f(z));
            dtp[(size_t)(row0 + rr)*D_IN + d] = z;
        }
    }
}

// Kernel 3: per-chunk scan partials. lane=(b,d,s,chunk). h_t = dA*h + dBx with clips.
// Stores P = prod(dA) and Q = chunk-final h.
__global__ __launch_bounds__(256) void scan1_k(
    const float* __restrict__ dtp, const float* __restrict__ Bss,
    const float* __restrict__ xc, float* __restrict__ Pq, float* __restrict__ Qq)
{
    int blk   = blockIdx.x;
    int chunk = blk & (CHUNKS - 1);
    int dg    = (blk >> 3) & 63;
    int b     = blk >> 9;
    int s  = threadIdx.x & 15;
    int dl = threadIdx.x >> 4;
    int d  = dg*16 + dl;
    float As = -(float)(s + 1);
    int t0  = chunk * CLEN;
    int itd = (b*T_LEN + t0)*D_IN + d;
    int its = (b*T_LEN + t0)*D_ST + s;
    float h = 0.0f, P = 1.0f;
    float dtv = dtp[itd], xv = xc[itd], bv = Bss[its];
    #pragma unroll 4
    for (int i = 0; i < CLEN; i++) {
        itd += D_IN; its += D_ST;
        float dtn = dtp[itd], xn = xc[itd], bn = Bss[its];  // prefetch (pads cover last)
        float dA  = fmaxf(__expf(dtv * As), 1e-38f);
        float dBx = fmaxf(dtv * bv * xv,   1e-38f);
        h = fmaf(dA, h, dBx);
        P *= dA;
        dtv = dtn; xv = xn; bv = bn;
    }
    int pq = ((b*D_IN + d)*D_ST + s)*CHUNKS + chunk;
    Pq[pq] = P; Qq[pq] = h;
}

// Kernel 4: prefix-combine P/Q, replay chunk, reduce over s (shfl within 16), write y.
__global__ __launch_bounds__(256) void scan2_k(
    const float* __restrict__ dtp, const float* __restrict__ Bss,
    const float* __restrict__ Css, const float* __restrict__ xc,
    const float* __restrict__ Pq, const float* __restrict__ Qq,
    const float* __restrict__ Dw, float* __restrict__ y)
{
    int blk   = blockIdx.x;
    int chunk = blk & (CHUNKS - 1);
    int dg    = (blk >> 3) & 63;
    int b     = blk >> 9;
    int s  = threadIdx.x & 15;
    int dl = threadIdx.x >> 4;
    int d  = dg*16 + dl;
    float As = -(float)(s + 1);

    int pqb = ((b*D_IN + d)*D_ST + s)*CHUNKS;
    float h = 0.0f;
    for (int c = 0; c < chunk; c++)               // uniform per block
        h = fmaf(Pq[pqb + c], h, Qq[pqb + c]);

    float Dv = Dw[d];
    int t0  = chunk * CLEN;
    int itd = (b*T_LEN + t0)*D_IN + d;
    int its = (b*T_LEN + t0)*D_ST + s;
    float dtv = dtp[itd], xv = xc[itd], bv = Bss[its], cv = Css[its];
    #pragma unroll 4
    for (int i = 0; i < CLEN; i++) {
        int itdc = itd;
        itd += D_IN; its += D_ST;
        float dtn = dtp[itd], xn = xc[itd], bn = Bss[its], cn = Css[its];
        float dA  = fmaxf(__expf(dtv * As), 1e-38f);
        float dBx = fmaxf(dtv * bv * xv,   1e-38f);
        h = fmaf(dA, h, dBx);
        float yp = cv * h;
        yp += __shfl_xor(yp, 1);
        yp += __shfl_xor(yp, 2);
        yp += __shfl_xor(yp, 4);
        yp += __shfl_xor(yp, 8);
        if (s == 0) y[itdc] = fmaf(Dv, xv, yp);
        dtv = dtn; xv = xn; bv = bn; cv = cn;
    }
}

extern "C" void kernel_launch(void* const* d_in, const int* in_sizes, int n_in,
                              void* d_out, int out_size, void* d_ws, size_t ws_size,
                              hipStream_t stream) {
    const float* x   = (const float*)d_in[0];
    const float* cw  = (const float*)d_in[1];
    const float* cb  = (const float*)d_in[2];
    const float* xpw = (const float*)d_in[3];
    const float* dtw = (const float*)d_in[4];
    const float* dtb = (const float*)d_in[5];
    const float* Dw  = (const float*)d_in[6];
    float* y = (float*)d_out;

    const size_t NTD = (size_t)BATCH * T_LEN * D_IN;      // 2M
    const size_t NTS = (size_t)BATCH * T_LEN * D_ST;      // 32768
    const size_t NPQ = (size_t)BATCH * D_IN * D_ST * CHUNKS; // 262144
    const size_t PAD = 1024;

    float* xc  = (float*)d_ws;
    float* dtp = xc  + NTD + PAD;
    float* Bss = dtp + NTD + PAD;
    float* Css = Bss + NTS + PAD;
    float* Pq  = Css + NTS + PAD;
    float* Qq  = Pq  + NPQ + PAD;

    conv_silu_k<<<(BATCH*(T_LEN/4)*D_IN)/256, 256, 0, stream>>>(x, cw, cb, xc);
    proj_dt_k<<<(BATCH*T_LEN)/8, 256, 0, stream>>>(xc, xpw, dtw, dtb, Bss, Css, dtp);
    scan1_k<<<BATCH*64*CHUNKS, 256, 0, stream>>>(dtp, Bss, xc, Pq, Qq);
    scan2_k<<<BATCH*64*CHUNKS, 256, 0, stream>>>(dtp, Bss, Css, xc, Pq, Qq, Dw, y);
}

// Round 3
// 158.660 us; speedup vs baseline: 1.1815x; 1.1815x over previous
//
#include <hip/hip_runtime.h>

#define BATCH 2
#define T_LEN 1024
#define D_IN  1024
#define D_ST  16
#define CHUNKS 16
#define CLEN  (T_LEN / CHUNKS)   // 64
#define DTILE 64
#define NCHAIN (BATCH * D_IN * 4)   // (b,d,sg) chains, each owns 4 s

__device__ __forceinline__ float softplus_f(float x) {
    return fmaxf(x, 0.0f) + __logf(1.0f + __expf(-fabsf(x)));
}

// Kernel 1: causal depthwise conv (K=4, left-pad 3) + bias + SiLU -> xc (B,T,D)
__global__ __launch_bounds__(256) void conv_silu_k(
    const float* __restrict__ x, const float* __restrict__ cw,
    const float* __restrict__ cb, float* __restrict__ xc)
{
    int tid = blockIdx.x * 256 + threadIdx.x;
    int d  = tid & (D_IN - 1);
    int g  = tid >> 10;
    int t0 = (g & (T_LEN/4 - 1)) << 2;
    int b  = g >> 8;
    float w0 = cw[d*4+0], w1 = cw[d*4+1], w2 = cw[d*4+2], w3 = cw[d*4+3];
    float bias = cb[d];
    int base = (b*T_LEN + t0)*D_IN + d;
    float xv[7];
    #pragma unroll
    for (int i = 0; i < 7; i++) {
        int t = t0 - 3 + i;
        xv[i] = (t >= 0) ? x[base + (i-3)*D_IN] : 0.0f;
    }
    #pragma unroll
    for (int r = 0; r < 4; r++) {
        float a = fmaf(xv[r], w0, fmaf(xv[r+1], w1, fmaf(xv[r+2], w2, fmaf(xv[r+3], w3, bias))));
        float sg = 1.0f / (1.0f + __expf(-a));
        xc[base + r*D_IN] = a * sg;
    }
}

// Kernel 2: proj + dt. grid = B*T/4 blocks; block 256 = 4 rows x (32 p x 2 half)
__global__ __launch_bounds__(256) void proj_dt_k(
    const float* __restrict__ xc, const float* __restrict__ xpw,
    const float* __restrict__ dtw, const float* __restrict__ dtb,
    float* __restrict__ Bss, float* __restrict__ Css, float* __restrict__ dtp)
{
    __shared__ float spart[4][32][2];
    __shared__ alignas(16) float Bsh[4][16];
    int tid = threadIdx.x;
    int r2 = tid >> 6, j = tid & 63, p = j & 31, half = j >> 5;
    int row0 = blockIdx.x * 4;
    int row  = row0 + r2;
    const float4* xr = (const float4*)(xc + (size_t)row * D_IN + half*512);
    const float4* wr = (const float4*)(xpw + (size_t)p * D_IN + half*512);
    float acc = 0.0f;
    #pragma unroll 8
    for (int k = 0; k < 128; k++) {
        float4 a = xr[k], w = wr[k];
        acc = fmaf(a.x, w.x, acc);
        acc = fmaf(a.y, w.y, acc);
        acc = fmaf(a.z, w.z, acc);
        acc = fmaf(a.w, w.w, acc);
    }
    spart[r2][p][half] = acc;
    __syncthreads();
    if (j < 32) {
        float v = spart[r2][j][0] + spart[r2][j][1];
        if (j < D_ST) { Bss[row*D_ST + j] = v; Bsh[r2][j] = v; }
        else          Css[row*D_ST + (j - D_ST)] = v;
    }
    __syncthreads();

    #pragma unroll
    for (int jd = 0; jd < 4; jd++) {
        int d = jd*256 + tid;
        const float4* wd = (const float4*)(dtw + (size_t)d * D_ST);
        float4 q0 = wd[0], q1 = wd[1], q2 = wd[2], q3 = wd[3];
        float bias = dtb[d];
        #pragma unroll
        for (int rr = 0; rr < 4; rr++) {
            const float4* Bp = (const float4*)&Bsh[rr][0];
            float4 b0 = Bp[0], b1 = Bp[1], b2 = Bp[2], b3 = Bp[3];
            float z = bias;
            z = fmaf(b0.x, q0.x, z); z = fmaf(b0.y, q0.y, z);
            z = fmaf(b0.z, q0.z, z); z = fmaf(b0.w, q0.w, z);
            z = fmaf(b1.x, q1.x, z); z = fmaf(b1.y, q1.y, z);
            z = fmaf(b1.z, q1.z, z); z = fmaf(b1.w, q1.w, z);
            z = fmaf(b2.x, q2.x, z); z = fmaf(b2.y, q2.y, z);
            z = fmaf(b2.z, q2.z, z); z = fmaf(b2.w, q2.w, z);
            z = fmaf(b3.x, q3.x, z); z = fmaf(b3.y, q3.y, z);
            z = fmaf(b3.z, q3.z, z); z = fmaf(b3.w, q3.w, z);
            z = softplus_f(softplus_f(z));
            dtp[(size_t)(row0 + rr)*D_IN + d] = z;
        }
    }
}

// Kernel 3: per-chunk scan partials, LDS-staged. block = 64 d x 4 sg; 4 s per lane.
__global__ __launch_bounds__(256) void scan1_k(
    const float* __restrict__ dtp, const float* __restrict__ Bss,
    const float* __restrict__ xc, float* __restrict__ Pq, float* __restrict__ Qq)
{
    __shared__ float s_dt[CLEN][DTILE];
    __shared__ float s_xc[CLEN][DTILE];
    __shared__ alignas(16) float s_B[CLEN][D_ST];
    int blk   = blockIdx.x;
    int chunk = blk & (CHUNKS - 1);
    int dg    = (blk >> 4) & (D_IN/DTILE - 1);
    int b     = blk >> 8;
    int tid = threadIdx.x;
    int t0 = chunk * CLEN, d0 = dg * DTILE;

    #pragma unroll
    for (int k = 0; k < 4; k++) {
        int fidx = tid + k*256;
        int ti = fidx >> 4, c4 = fidx & 15;
        size_t g = (size_t)(b*T_LEN + t0 + ti)*D_IN + d0;
        ((float4*)&s_dt[ti][0])[c4] = ((const float4*)(dtp + g))[c4];
        ((float4*)&s_xc[ti][0])[c4] = ((const float4*)(xc  + g))[c4];
    }
    {
        int ti = tid >> 2, c4 = tid & 3;
        ((float4*)&s_B[ti][0])[c4] =
            ((const float4*)(Bss + (size_t)(b*T_LEN + t0 + ti)*D_ST))[c4];
    }
    __syncthreads();

    int sg = tid & 3, dl = tid >> 2;
    float a0 = -(float)(sg*4+1), a1 = -(float)(sg*4+2);
    float a2 = -(float)(sg*4+3), a3 = -(float)(sg*4+4);
    float h0 = 0, h1 = 0, h2 = 0, h3 = 0;
    float p0 = 1, p1 = 1, p2 = 1, p3 = 1;
    #pragma unroll 4
    for (int i = 0; i < CLEN; i++) {
        float dt = s_dt[i][dl], xv = s_xc[i][dl];
        float4 bv = *((const float4*)&s_B[i][sg*4]);
        float e0 = fmaxf(__expf(dt*a0), 1e-38f);
        float e1 = fmaxf(__expf(dt*a1), 1e-38f);
        float e2 = fmaxf(__expf(dt*a2), 1e-38f);
        float e3 = fmaxf(__expf(dt*a3), 1e-38f);
        float q0 = fmaxf(dt*bv.x*xv, 1e-38f);
        float q1 = fmaxf(dt*bv.y*xv, 1e-38f);
        float q2 = fmaxf(dt*bv.z*xv, 1e-38f);
        float q3 = fmaxf(dt*bv.w*xv, 1e-38f);
        h0 = fmaf(e0, h0, q0); p0 *= e0;
        h1 = fmaf(e1, h1, q1); p1 *= e1;
        h2 = fmaf(e2, h2, q2); p2 *= e2;
        h3 = fmaf(e3, h3, q3); p3 *= e3;
    }
    int chain = (b*D_IN + d0 + dl)*4 + sg;
    float4 P4 = {p0,p1,p2,p3}, Q4 = {h0,h1,h2,h3};
    ((float4*)Pq)[(size_t)chain*CHUNKS + chunk] = P4;
    ((float4*)Qq)[(size_t)chain*CHUNKS + chunk] = Q4;
}

// Kernel 3.5: chunk-start states. 1 thread per chain; loads are independent (MLP).
__global__ __launch_bounds__(256) void scan_mid_k(
    const float* __restrict__ Pq, const float* __restrict__ Qq, float* __restrict__ H0)
{
    int chain = blockIdx.x*256 + threadIdx.x;
    const float4* P4 = (const float4*)Pq + (size_t)chain*CHUNKS;
    const float4* Q4 = (const float4*)Qq + (size_t)chain*CHUNKS;
    float4* O = (float4*)H0 + (size_t)chain*CHUNKS;
    float4 h = {0,0,0,0};
    #pragma unroll
    for (int c = 0; c < CHUNKS; c++) {
        float4 p = P4[c], q = Q4[c];
        O[c] = h;
        h.x = fmaf(p.x, h.x, q.x);
        h.y = fmaf(p.y, h.y, q.y);
        h.z = fmaf(p.z, h.z, q.z);
        h.w = fmaf(p.w, h.w, q.w);
    }
}

// Kernel 4: replay with known chunk-start state, reduce over s, write y.
__global__ __launch_bounds__(256) void scan2_k(
    const float* __restrict__ dtp, const float* __restrict__ Bss,
    const float* __restrict__ Css, const float* __restrict__ xc,
    const float* __restrict__ H0, const float* __restrict__ Dw,
    float* __restrict__ y)
{
    __shared__ float s_dt[CLEN][DTILE];
    __shared__ float s_xc[CLEN][DTILE];
    __shared__ alignas(16) float s_B[CLEN][D_ST];
    __shared__ alignas(16) float s_C[CLEN][D_ST];
    int blk   = blockIdx.x;
    int chunk = blk & (CHUNKS - 1);
    int dg    = (blk >> 4) & (D_IN/DTILE - 1);
    int b     = blk >> 8;
    int tid = threadIdx.x;
    int t0 = chunk * CLEN, d0 = dg * DTILE;

    #pragma unroll
    for (int k = 0; k < 4; k++) {
        int fidx = tid + k*256;
        int ti = fidx >> 4, c4 = fidx & 15;
        size_t g = (size_t)(b*T_LEN + t0 + ti)*D_IN + d0;
        ((float4*)&s_dt[ti][0])[c4] = ((const float4*)(dtp + g))[c4];
        ((float4*)&s_xc[ti][0])[c4] = ((const float4*)(xc  + g))[c4];
    }
    {
        int ti = tid >> 2, c4 = tid & 3;
        size_t g = (size_t)(b*T_LEN + t0 + ti)*D_ST;
        ((float4*)&s_B[ti][0])[c4] = ((const float4*)(Bss + g))[c4];
        ((float4*)&s_C[ti][0])[c4] = ((const float4*)(Css + g))[c4];
    }
    __syncthreads();

    int sg = tid & 3, dl = tid >> 2;
    float a0 = -(float)(sg*4+1), a1 = -(float)(sg*4+2);
    float a2 = -(float)(sg*4+3), a3 = -(float)(sg*4+4);
    int chain = (b*D_IN + d0 + dl)*4 + sg;
    float4 h = ((const float4*)H0)[(size_t)chain*CHUNKS + chunk];
    float Dv = Dw[d0 + dl];
    size_t orow = (size_t)(b*T_LEN + t0)*D_IN + d0 + dl;

    #pragma unroll 4
    for (int i = 0; i < CLEN; i++) {
        float dt = s_dt[i][dl], xv = s_xc[i][dl];
        float4 bv = *((const float4*)&s_B[i][sg*4]);
        float4 cv = *((const float4*)&s_C[i][sg*4]);
        float e0 = fmaxf(__expf(dt*a0), 1e-38f);
        float e1 = fmaxf(__expf(dt*a1), 1e-38f);
        float e2 = fmaxf(__expf(dt*a2), 1e-38f);
        float e3 = fmaxf(__expf(dt*a3), 1e-38f);
        float q0 = fmaxf(dt*bv.x*xv, 1e-38f);
        float q1 = fmaxf(dt*bv.y*xv, 1e-38f);
        float q2 = fmaxf(dt*bv.z*xv, 1e-38f);
        float q3 = fmaxf(dt*bv.w*xv, 1e-38f);
        h.x = fmaf(e0, h.x, q0);
        h.y = fmaf(e1, h.y, q1);
        h.z = fmaf(e2, h.z, q2);
        h.w = fmaf(e3, h.w, q3);
        float yp = cv.x*h.x;
        yp = fmaf(cv.y, h.y, yp);
        yp = fmaf(cv.z, h.z, yp);
        yp = fmaf(cv.w, h.w, yp);
        yp += __shfl_xor(yp, 1);
        yp += __shfl_xor(yp, 2);
        if (sg == 0) y[orow + (size_t)i*D_IN] = fmaf(Dv, xv, yp);
    }
}

extern "C" void kernel_launch(void* const* d_in, const int* in_sizes, int n_in,
                              void* d_out, int out_size, void* d_ws, size_t ws_size,
                              hipStream_t stream) {
    const float* x   = (const float*)d_in[0];
    const float* cw  = (const float*)d_in[1];
    const float* cb  = (const float*)d_in[2];
    const float* xpw = (const float*)d_in[3];
    const float* dtw = (const float*)d_in[4];
    const float* dtb = (const float*)d_in[5];
    const float* Dw  = (const float*)d_in[6];
    float* y = (float*)d_out;

    const size_t NTD = (size_t)BATCH * T_LEN * D_IN;        // 2M
    const size_t NTS = (size_t)BATCH * T_LEN * D_ST;        // 32768
    const size_t NPQ = (size_t)NCHAIN * CHUNKS * 4;         // 524288
    const size_t PAD = 1024;

    float* xc  = (float*)d_ws;
    float* dtp = xc  + NTD + PAD;
    float* Bss = dtp + NTD + PAD;
    float* Css = Bss + NTS + PAD;
    float* Pq  = Css + NTS + PAD;
    float* Qq  = Pq  + NPQ + PAD;
    float* H0  = Qq  + NPQ + PAD;

    conv_silu_k<<<(BATCH*(T_LEN/4)*D_IN)/256, 256, 0, stream>>>(x, cw, cb, xc);
    proj_dt_k<<<(BATCH*T_LEN)/4, 256, 0, stream>>>(xc, xpw, dtw, dtb, Bss, Css, dtp);
    scan1_k<<<BATCH*(D_IN/DTILE)*CHUNKS, 256, 0, stream>>>(dtp, Bss, xc, Pq, Qq);
    scan_mid_k<<<NCHAIN/256, 256, 0, stream>>>(Pq, Qq, H0);
    scan2_k<<<BATCH*(D_IN/DTILE)*CHUNKS, 256, 0, stream>>>(dtp, Bss, Css, xc, H0, Dw, y);
}

// Round 4
// 133.000 us; speedup vs baseline: 1.4094x; 1.1929x over previous
//
#include <hip/hip_runtime.h>

#define BATCH 2
#define T_LEN 1024
#define D_IN  1024
#define D_ST  16
#define CHUNKS 16
#define CLEN  (T_LEN / CHUNKS)   // 64
#define DTILE 64
#define NCHAIN (BATCH * D_IN * 4)   // (b,d,sg) chains, each owns 4 s

__device__ __forceinline__ float softplus_f(float x) {
    return fmaxf(x, 0.0f) + __logf(1.0f + __expf(-fabsf(x)));
}

// Kernel 1: causal depthwise conv (K=4, left-pad 3) + bias + SiLU -> xc (B,T,D)
__global__ __launch_bounds__(256) void conv_silu_k(
    const float* __restrict__ x, const float* __restrict__ cw,
    const float* __restrict__ cb, float* __restrict__ xc)
{
    int tid = blockIdx.x * 256 + threadIdx.x;
    int d  = tid & (D_IN - 1);
    int g  = tid >> 10;
    int t0 = (g & (T_LEN/4 - 1)) << 2;
    int b  = g >> 8;
    float w0 = cw[d*4+0], w1 = cw[d*4+1], w2 = cw[d*4+2], w3 = cw[d*4+3];
    float bias = cb[d];
    int base = (b*T_LEN + t0)*D_IN + d;
    float xv[7];
    #pragma unroll
    for (int i = 0; i < 7; i++) {
        int t = t0 - 3 + i;
        xv[i] = (t >= 0) ? x[base + (i-3)*D_IN] : 0.0f;
    }
    #pragma unroll
    for (int r = 0; r < 4; r++) {
        float a = fmaf(xv[r], w0, fmaf(xv[r+1], w1, fmaf(xv[r+2], w2, fmaf(xv[r+3], w3, bias))));
        float sg = 1.0f / (1.0f + __expf(-a));
        xc[base + r*D_IN] = a * sg;
    }
}

// Kernel 2: proj + dt. 2 rows/block, 1024 blocks. 256 thr = 32 p x 8 kg.
// Interleaved k-split: float4 idx = kg + j*8 -> contiguous 128B per 8 kg lanes.
__global__ __launch_bounds__(256) void proj_dt_k(
    const float* __restrict__ xc, const float* __restrict__ xpw,
    const float* __restrict__ dtw, const float* __restrict__ dtb,
    float* __restrict__ Bss, float* __restrict__ Css, float* __restrict__ dtp)
{
    __shared__ alignas(16) float Bsh[2][16];
    int tid = threadIdx.x;
    int p  = tid >> 3;
    int kg = tid & 7;
    int row0 = blockIdx.x * 2;
    const float4* x0 = (const float4*)(xc + (size_t)row0 * D_IN);
    const float4* x1 = (const float4*)(xc + (size_t)(row0 + 1) * D_IN);
    const float4* wr = (const float4*)(xpw + (size_t)p * D_IN);
    float4 acc0 = {0,0,0,0}, acc1 = {0,0,0,0};
    #pragma unroll
    for (int j = 0; j < 32; j++) {
        int idx = kg + j*8;
        float4 w = wr[idx];
        float4 a = x0[idx];
        float4 c = x1[idx];
        acc0.x = fmaf(a.x, w.x, acc0.x);
        acc0.y = fmaf(a.y, w.y, acc0.y);
        acc0.z = fmaf(a.z, w.z, acc0.z);
        acc0.w = fmaf(a.w, w.w, acc0.w);
        acc1.x = fmaf(c.x, w.x, acc1.x);
        acc1.y = fmaf(c.y, w.y, acc1.y);
        acc1.z = fmaf(c.z, w.z, acc1.z);
        acc1.w = fmaf(c.w, w.w, acc1.w);
    }
    float v0 = (acc0.x + acc0.y) + (acc0.z + acc0.w);
    float v1 = (acc1.x + acc1.y) + (acc1.z + acc1.w);
    v0 += __shfl_xor(v0, 1); v0 += __shfl_xor(v0, 2); v0 += __shfl_xor(v0, 4);
    v1 += __shfl_xor(v1, 1); v1 += __shfl_xor(v1, 2); v1 += __shfl_xor(v1, 4);
    if (kg == 0) {
        if (p < D_ST) {
            Bss[(size_t)row0*D_ST + p] = v0;
            Bss[(size_t)(row0+1)*D_ST + p] = v1;
            Bsh[0][p] = v0;
            Bsh[1][p] = v1;
        } else {
            Css[(size_t)row0*D_ST + (p - D_ST)] = v0;
            Css[(size_t)(row0+1)*D_ST + (p - D_ST)] = v1;
        }
    }
    __syncthreads();

    const float4* B0 = (const float4*)&Bsh[0][0];
    const float4* B1 = (const float4*)&Bsh[1][0];
    float4 b00 = B0[0], b01 = B0[1], b02 = B0[2], b03 = B0[3];
    float4 b10 = B1[0], b11 = B1[1], b12 = B1[2], b13 = B1[3];
    #pragma unroll
    for (int jd = 0; jd < 4; jd++) {
        int d = jd*256 + tid;
        const float4* wd = (const float4*)(dtw + (size_t)d * D_ST);
        float4 q0 = wd[0], q1 = wd[1], q2 = wd[2], q3 = wd[3];
        float bias = dtb[d];
        float z0 = bias, z1 = bias;
        z0 = fmaf(b00.x, q0.x, z0); z0 = fmaf(b00.y, q0.y, z0);
        z0 = fmaf(b00.z, q0.z, z0); z0 = fmaf(b00.w, q0.w, z0);
        z0 = fmaf(b01.x, q1.x, z0); z0 = fmaf(b01.y, q1.y, z0);
        z0 = fmaf(b01.z, q1.z, z0); z0 = fmaf(b01.w, q1.w, z0);
        z0 = fmaf(b02.x, q2.x, z0); z0 = fmaf(b02.y, q2.y, z0);
        z0 = fmaf(b02.z, q2.z, z0); z0 = fmaf(b02.w, q2.w, z0);
        z0 = fmaf(b03.x, q3.x, z0); z0 = fmaf(b03.y, q3.y, z0);
        z0 = fmaf(b03.z, q3.z, z0); z0 = fmaf(b03.w, q3.w, z0);
        z1 = fmaf(b10.x, q0.x, z1); z1 = fmaf(b10.y, q0.y, z1);
        z1 = fmaf(b10.z, q0.z, z1); z1 = fmaf(b10.w, q0.w, z1);
        z1 = fmaf(b11.x, q1.x, z1); z1 = fmaf(b11.y, q1.y, z1);
        z1 = fmaf(b11.z, q1.z, z1); z1 = fmaf(b11.w, q1.w, z1);
        z1 = fmaf(b12.x, q2.x, z1); z1 = fmaf(b12.y, q2.y, z1);
        z1 = fmaf(b12.z, q2.z, z1); z1 = fmaf(b12.w, q2.w, z1);
        z1 = fmaf(b13.x, q3.x, z1); z1 = fmaf(b13.y, q3.y, z1);
        z1 = fmaf(b13.z, q3.z, z1); z1 = fmaf(b13.w, q3.w, z1);
        z0 = softplus_f(softplus_f(z0));
        z1 = softplus_f(softplus_f(z1));
        dtp[(size_t)row0*D_IN + d] = z0;
        dtp[(size_t)(row0+1)*D_IN + d] = z1;
    }
}

// Kernel 3: per-chunk scan partials, LDS-staged. block = 64 d x 4 sg; 4 s per lane.
__global__ __launch_bounds__(256) void scan1_k(
    const float* __restrict__ dtp, const float* __restrict__ Bss,
    const float* __restrict__ xc, float* __restrict__ Pq, float* __restrict__ Qq)
{
    __shared__ float s_dt[CLEN][DTILE];
    __shared__ float s_xc[CLEN][DTILE];
    __shared__ alignas(16) float s_B[CLEN][D_ST];
    int blk   = blockIdx.x;
    int chunk = blk & (CHUNKS - 1);
    int dg    = (blk >> 4) & (D_IN/DTILE - 1);
    int b     = blk >> 8;
    int tid = threadIdx.x;
    int t0 = chunk * CLEN, d0 = dg * DTILE;

    #pragma unroll
    for (int k = 0; k < 4; k++) {
        int fidx = tid + k*256;
        int ti = fidx >> 4, c4 = fidx & 15;
        size_t g = (size_t)(b*T_LEN + t0 + ti)*D_IN + d0;
        ((float4*)&s_dt[ti][0])[c4] = ((const float4*)(dtp + g))[c4];
        ((float4*)&s_xc[ti][0])[c4] = ((const float4*)(xc  + g))[c4];
    }
    {
        int ti = tid >> 2, c4 = tid & 3;
        ((float4*)&s_B[ti][0])[c4] =
            ((const float4*)(Bss + (size_t)(b*T_LEN + t0 + ti)*D_ST))[c4];
    }
    __syncthreads();

    int sg = tid & 3, dl = tid >> 2;
    float a0 = -(float)(sg*4+1), a1 = -(float)(sg*4+2);
    float a2 = -(float)(sg*4+3), a3 = -(float)(sg*4+4);
    float h0 = 0, h1 = 0, h2 = 0, h3 = 0;
    float p0 = 1, p1 = 1, p2 = 1, p3 = 1;
    #pragma unroll 4
    for (int i = 0; i < CLEN; i++) {
        float dt = s_dt[i][dl], xv = s_xc[i][dl];
        float4 bv = *((const float4*)&s_B[i][sg*4]);
        float e0 = fmaxf(__expf(dt*a0), 1e-38f);
        float e1 = fmaxf(__expf(dt*a1), 1e-38f);
        float e2 = fmaxf(__expf(dt*a2), 1e-38f);
        float e3 = fmaxf(__expf(dt*a3), 1e-38f);
        float q0 = fmaxf(dt*bv.x*xv, 1e-38f);
        float q1 = fmaxf(dt*bv.y*xv, 1e-38f);
        float q2 = fmaxf(dt*bv.z*xv, 1e-38f);
        float q3 = fmaxf(dt*bv.w*xv, 1e-38f);
        h0 = fmaf(e0, h0, q0); p0 *= e0;
        h1 = fmaf(e1, h1, q1); p1 *= e1;
        h2 = fmaf(e2, h2, q2); p2 *= e2;
        h3 = fmaf(e3, h3, q3); p3 *= e3;
    }
    int chain = (b*D_IN + d0 + dl)*4 + sg;
    float4 P4 = {p0,p1,p2,p3}, Q4 = {h0,h1,h2,h3};
    ((float4*)Pq)[(size_t)chain*CHUNKS + chunk] = P4;
    ((float4*)Qq)[(size_t)chain*CHUNKS + chunk] = Q4;
}

// Kernel 3.5: chunk-start states. 1 thread per chain; loads are independent (MLP).
__global__ __launch_bounds__(256) void scan_mid_k(
    const float* __restrict__ Pq, const float* __restrict__ Qq, float* __restrict__ H0)
{
    int chain = blockIdx.x*256 + threadIdx.x;
    const float4* P4 = (const float4*)Pq + (size_t)chain*CHUNKS;
    const float4* Q4 = (const float4*)Qq + (size_t)chain*CHUNKS;
    float4* O = (float4*)H0 + (size_t)chain*CHUNKS;
    float4 h = {0,0,0,0};
    #pragma unroll
    for (int c = 0; c < CHUNKS; c++) {
        float4 p = P4[c], q = Q4[c];
        O[c] = h;
        h.x = fmaf(p.x, h.x, q.x);
        h.y = fmaf(p.y, h.y, q.y);
        h.z = fmaf(p.z, h.z, q.z);
        h.w = fmaf(p.w, h.w, q.w);
    }
}

// Kernel 4: replay with known chunk-start state, reduce over s, write y.
__global__ __launch_bounds__(256) void scan2_k(
    const float* __restrict__ dtp, const float* __restrict__ Bss,
    const float* __restrict__ Css, const float* __restrict__ xc,
    const float* __restrict__ H0, const float* __restrict__ Dw,
    float* __restrict__ y)
{
    __shared__ float s_dt[CLEN][DTILE];
    __shared__ float s_xc[CLEN][DTILE];
    __shared__ alignas(16) float s_B[CLEN][D_ST];
    __shared__ alignas(16) float s_C[CLEN][D_ST];
    int blk   = blockIdx.x;
    int chunk = blk & (CHUNKS - 1);
    int dg    = (blk >> 4) & (D_IN/DTILE - 1);
    int b     = blk >> 8;
    int tid = threadIdx.x;
    int t0 = chunk * CLEN, d0 = dg * DTILE;

    #pragma unroll
    for (int k = 0; k < 4; k++) {
        int fidx = tid + k*256;
        int ti = fidx >> 4, c4 = fidx & 15;
        size_t g = (size_t)(b*T_LEN + t0 + ti)*D_IN + d0;
        ((float4*)&s_dt[ti][0])[c4] = ((const float4*)(dtp + g))[c4];
        ((float4*)&s_xc[ti][0])[c4] = ((const float4*)(xc  + g))[c4];
    }
    {
        int ti = tid >> 2, c4 = tid & 3;
        size_t g = (size_t)(b*T_LEN + t0 + ti)*D_ST;
        ((float4*)&s_B[ti][0])[c4] = ((const float4*)(Bss + g))[c4];
        ((float4*)&s_C[ti][0])[c4] = ((const float4*)(Css + g))[c4];
    }
    __syncthreads();

    int sg = tid & 3, dl = tid >> 2;
    float a0 = -(float)(sg*4+1), a1 = -(float)(sg*4+2);
    float a2 = -(float)(sg*4+3), a3 = -(float)(sg*4+4);
    int chain = (b*D_IN + d0 + dl)*4 + sg;
    float4 h = ((const float4*)H0)[(size_t)chain*CHUNKS + chunk];
    float Dv = Dw[d0 + dl];
    size_t orow = (size_t)(b*T_LEN + t0)*D_IN + d0 + dl;

    #pragma unroll 4
    for (int i = 0; i < CLEN; i++) {
        float dt = s_dt[i][dl], xv = s_xc[i][dl];
        float4 bv = *((const float4*)&s_B[i][sg*4]);
        float4 cv = *((const float4*)&s_C[i][sg*4]);
        float e0 = fmaxf(__expf(dt*a0), 1e-38f);
        float e1 = fmaxf(__expf(dt*a1), 1e-38f);
        float e2 = fmaxf(__expf(dt*a2), 1e-38f);
        float e3 = fmaxf(__expf(dt*a3), 1e-38f);
        float q0 = fmaxf(dt*bv.x*xv, 1e-38f);
        float q1 = fmaxf(dt*bv.y*xv, 1e-38f);
        float q2 = fmaxf(dt*bv.z*xv, 1e-38f);
        float q3 = fmaxf(dt*bv.w*xv, 1e-38f);
        h.x = fmaf(e0, h.x, q0);
        h.y = fmaf(e1, h.y, q1);
        h.z = fmaf(e2, h.z, q2);
        h.w = fmaf(e3, h.w, q3);
        float yp = cv.x*h.x;
        yp = fmaf(cv.y, h.y, yp);
        yp = fmaf(cv.z, h.z, yp);
        yp = fmaf(cv.w, h.w, yp);
        yp += __shfl_xor(yp, 1);
        yp += __shfl_xor(yp, 2);
        if (sg == 0) y[orow + (size_t)i*D_IN] = fmaf(Dv, xv, yp);
    }
}

extern "C" void kernel_launch(void* const* d_in, const int* in_sizes, int n_in,
                              void* d_out, int out_size, void* d_ws, size_t ws_size,
                              hipStream_t stream) {
    const float* x   = (const float*)d_in[0];
    const float* cw  = (const float*)d_in[1];
    const float* cb  = (const float*)d_in[2];
    const float* xpw = (const float*)d_in[3];
    const float* dtw = (const float*)d_in[4];
    const float* dtb = (const float*)d_in[5];
    const float* Dw  = (const float*)d_in[6];
    float* y = (float*)d_out;

    const size_t NTD = (size_t)BATCH * T_LEN * D_IN;        // 2M
    const size_t NTS = (size_t)BATCH * T_LEN * D_ST;        // 32768
    const size_t NPQ = (size_t)NCHAIN * CHUNKS * 4;         // 524288
    const size_t PAD = 1024;

    float* xc  = (float*)d_ws;
    float* dtp = xc  + NTD + PAD;
    float* Bss = dtp + NTD + PAD;
    float* Css = Bss + NTS + PAD;
    float* Pq  = Css + NTS + PAD;
    float* Qq  = Pq  + NPQ + PAD;
    float* H0  = Qq  + NPQ + PAD;

    conv_silu_k<<<(BATCH*(T_LEN/4)*D_IN)/256, 256, 0, stream>>>(x, cw, cb, xc);
    proj_dt_k<<<(BATCH*T_LEN)/2, 256, 0, stream>>>(xc, xpw, dtw, dtb, Bss, Css, dtp);
    scan1_k<<<BATCH*(D_IN/DTILE)*CHUNKS, 256, 0, stream>>>(dtp, Bss, xc, Pq, Qq);
    scan_mid_k<<<NCHAIN/256, 256, 0, stream>>>(Pq, Qq, H0);
    scan2_k<<<BATCH*(D_IN/DTILE)*CHUNKS, 256, 0, stream>>>(dtp, Bss, Css, xc, H0, Dw, y);
}